// Round 1
// baseline (2092.446 us; speedup 1.0000x reference)
//
#include <hip/hip_runtime.h>
#include <cstddef>
#include <cstdint>
#include <math.h>

#define S_LEN 2048
#define DIM 1024
#define NH 16
#define HD 64
#define NFREQ 16

// ---------------------------------------------------------------------------
// GEMM: C = A @ W^T + bias.  A: (2048,1024) row-major, W: (1024,1024) row-major.
// mode 0: C row-major (s, DIM).  mode 1: C head-major [h][s][d].
// 64x64 block tile, BK=16, 256 threads, 4x4 micro-tile.
// ---------------------------------------------------------------------------
struct GemmBatch {
  const float* A[6];
  const float* W[6];
  const float* bias[6];
  float* C[6];
};

__global__ __launch_bounds__(256) void gemm_bias_kernel(GemmBatch gb, int mode)
{
  const int z = blockIdx.z;
  const float* __restrict__ A = gb.A[z];
  const float* __restrict__ W = gb.W[z];
  const float* __restrict__ bias = gb.bias[z];
  float* __restrict__ C = gb.C[z];
  const int K = DIM;

  __shared__ float As[16][65];   // [k][m], stride 65 breaks bank conflicts
  __shared__ float Bs[16][65];   // [k][n]

  const int t  = threadIdx.x;
  const int tr = t >> 4;         // 0..15
  const int tc = t & 15;         // 0..15
  const int m0 = blockIdx.y * 64;
  const int n0 = blockIdx.x * 64;
  const int lm = t >> 4;         // load row 0..15 (+16q)
  const int lk = t & 15;         // load k 0..15

  float acc[4][4] = {};

  for (int k0 = 0; k0 < K; k0 += 16) {
#pragma unroll
    for (int q = 0; q < 4; q++) {
      As[lk][lm + 16*q] = A[(size_t)(m0 + lm + 16*q) * K + (k0 + lk)];
      Bs[lk][lm + 16*q] = W[(size_t)(n0 + lm + 16*q) * K + (k0 + lk)];
    }
    __syncthreads();
#pragma unroll
    for (int kk = 0; kk < 16; kk++) {
      float a[4], b[4];
#pragma unroll
      for (int i = 0; i < 4; i++) a[i] = As[kk][tr*4 + i];
#pragma unroll
      for (int j = 0; j < 4; j++) b[j] = Bs[kk][tc*4 + j];
#pragma unroll
      for (int i = 0; i < 4; i++)
#pragma unroll
        for (int j = 0; j < 4; j++)
          acc[i][j] += a[i] * b[j];
    }
    __syncthreads();
  }

#pragma unroll
  for (int i = 0; i < 4; i++) {
    const int m = m0 + tr*4 + i;
#pragma unroll
    for (int j = 0; j < 4; j++) {
      const int n = n0 + tc*4 + j;
      const float v = acc[i][j] + bias[n];
      if (mode == 0) {
        C[(size_t)m * DIM + n] = v;
      } else {
        const int hh = n >> 6, d = n & 63;
        C[((size_t)hh * S_LEN + m) * HD + d] = v;
      }
    }
  }
}

// ---------------------------------------------------------------------------
// RoPE (interleaved) on first 32 dims of each head, in-place on 4 tensors.
// Tensors are head-major [h][s][d].
// ---------------------------------------------------------------------------
__global__ __launch_bounds__(256) void rope_kernel(
    float* q_r, float* k_r, float* q_i, float* k_i,
    const float* __restrict__ freqs)
{
  const int gid = blockIdx.x * 256 + threadIdx.x;  // 4*16*2048*16 = 2097152
  const int j  = gid & 15;
  const int s  = (gid >> 4) & (S_LEN - 1);
  const int h  = (gid >> 15) & (NH - 1);
  const int tz = gid >> 19;
  float* buf = (tz == 0) ? q_r : (tz == 1) ? k_r : (tz == 2) ? q_i : k_i;

  const float ang = (float)s * freqs[j];
  float sn, cs;
  sincosf(ang, &sn, &cs);

  const size_t base = ((size_t)h * S_LEN + s) * HD + 2*j;
  const float x1 = buf[base];
  const float x2 = buf[base + 1];
  buf[base]     = x1 * cs - x2 * sn;
  buf[base + 1] = x1 * sn + x2 * cs;
}

// ---------------------------------------------------------------------------
// Entanglement (head mix via E[h][x]) + phase rotation. z=0 -> Q, z=1 -> K.
// in/out are head-major [h][s][d]; each thread handles one (s,d) for all heads.
// ---------------------------------------------------------------------------
__global__ __launch_bounds__(256) void entangle_kernel(
    const float* __restrict__ qr_in, const float* __restrict__ qi_in,
    float* __restrict__ qr_out, float* __restrict__ qi_out,
    const float* __restrict__ kr_in, const float* __restrict__ ki_in,
    float* __restrict__ kr_out, float* __restrict__ ki_out,
    const float* __restrict__ E, const float* __restrict__ phase)
{
  const int z = blockIdx.z;
  const float* inR = z ? kr_in : qr_in;
  const float* inI = z ? ki_in : qi_in;
  float* outR = z ? kr_out : qr_out;
  float* outI = z ? ki_out : qi_out;

  __shared__ float Es[NH * NH];
  const int t = threadIdx.x;
  Es[t] = E[t];          // 256 == NH*NH
  __syncthreads();

  const int idx = blockIdx.x * 256 + t;   // 0 .. 2048*64-1
  const int s = idx >> 6;
  const int d = idx & 63;

  float vr[NH], vi[NH];
#pragma unroll
  for (int h = 0; h < NH; h++) {
    const size_t off = ((size_t)h * S_LEN + s) * HD + d;
    vr[h] = inR[off];
    vi[h] = inI[off];
  }

#pragma unroll
  for (int x = 0; x < NH; x++) {
    float er = 0.f, ei = 0.f;
#pragma unroll
    for (int h = 0; h < NH; h++) {
      const float e = Es[h * NH + x];
      er += vr[h] * e;
      ei += vi[h] * e;
    }
    const float ph = phase[x * HD + d];
    float ps, pc;
    sincosf(ph, &ps, &pc);
    const size_t off = ((size_t)x * S_LEN + s) * HD + d;
    outR[off] = er * pc - ei * ps;
    outI[off] = er * ps + ei * pc;
  }
}

// ---------------------------------------------------------------------------
// Flash-style causal attention over magnitude-logits.
//   k1 = Qr.Kr, k2 = Qi.Ki, cross = Qr.Ki + Qi.Kr  (= k3-k1-k2)
//   ar = scale*(k1-k2) + eps*scale*cross ; ai = scale*cross - eps*scale*(k1-k2)
//   L = sqrt(ar^2+ai^2+1e-6) * strength/temp ; masked j>i -> -1e30
// BM=BN=32 tiles, 256 threads: score micro 2x2 (tr row pair, tc col pair),
// output micro 2 rows x 4 cols for both real/imag. Online softmax state per
// row kept redundantly in the 16 lanes sharing the row (shuffle reductions).
// Output written row-major (s, DIM) with head column offset.
// ---------------------------------------------------------------------------
__global__ __launch_bounds__(256) void flash_kernel(
    const float* __restrict__ Qr, const float* __restrict__ Qi,
    const float* __restrict__ Kr, const float* __restrict__ Ki,
    const float* __restrict__ Vr, const float* __restrict__ Vi,
    float* __restrict__ Or, float* __restrict__ Oi,
    const float* __restrict__ p_is, const float* __restrict__ p_at,
    const float* __restrict__ p_ce)
{
  constexpr int BM = 32, BN = 32;
  __shared__ float Qr_s[BM][HD + 1], Qi_s[BM][HD + 1];
  __shared__ float Kr_s[BN][HD + 1], Ki_s[BN][HD + 1];
  __shared__ float Vr_s[BN][HD + 1], Vi_s[BN][HD + 1];
  __shared__ float P_s[BM][BN + 1];

  const int t  = threadIdx.x;
  const int tr = t >> 4;     // rows tr*2 + {0,1}
  const int tc = t & 15;     // score cols tc*2+{0,1}; out cols tc*4+{0..3}
  const int h  = blockIdx.y;
  const int i0 = blockIdx.x * BM;

  const float strength = 1.f / (1.f + expf(-p_is[0]));
  const float temp     = fmaxf(expf(p_at[0]), 0.1f);
  const float cfac     = strength / temp;
  const float eps      = 0.03f / (1.f + expf(-p_ce[0]));
  const float scale    = 0.125f;   // 1/sqrt(64)

  const size_t qbase = ((size_t)h * S_LEN + i0) * HD;
  for (int idx = t; idx < BM * HD; idx += 256) {
    const int r = idx >> 6, d = idx & 63;
    Qr_s[r][d] = Qr[qbase + idx];
    Qi_s[r][d] = Qi[qbase + idx];
  }

  const int r0 = tr * 2, r1 = tr * 2 + 1;
  const int c0 = tc * 2, c1 = tc * 2 + 1;

  float m0 = -1e30f, m1 = -1e30f;
  float l0 = 0.f, l1 = 0.f;
  float aR0[4] = {}, aR1[4] = {}, aI0[4] = {}, aI1[4] = {};

  const int ntiles = (i0 >> 5) + 1;
  for (int jt = 0; jt < ntiles; jt++) {
    const int j0 = jt * BN;
    const size_t kbase = ((size_t)h * S_LEN + j0) * HD;

    __syncthreads();   // prev PV done (and on iter 0 nothing to protect)
    for (int idx = t; idx < BN * HD; idx += 256) {
      const int r = idx >> 6, d = idx & 63;
      Kr_s[r][d] = Kr[kbase + idx];
      Ki_s[r][d] = Ki[kbase + idx];
      Vr_s[r][d] = Vr[kbase + idx];
      Vi_s[r][d] = Vi[kbase + idx];
    }
    __syncthreads();   // Q (iter 0) and K/V ready

    // ---- scores ----
    float k1v[2][2] = {}, k2v[2][2] = {}, kxv[2][2] = {};
    for (int d = 0; d < HD; d++) {
      const float qr0 = Qr_s[r0][d], qr1 = Qr_s[r1][d];
      const float qi0 = Qi_s[r0][d], qi1 = Qi_s[r1][d];
      const float kr0 = Kr_s[c0][d], kr1 = Kr_s[c1][d];
      const float ki0 = Ki_s[c0][d], ki1 = Ki_s[c1][d];
      k1v[0][0] += qr0 * kr0; k1v[0][1] += qr0 * kr1;
      k1v[1][0] += qr1 * kr0; k1v[1][1] += qr1 * kr1;
      k2v[0][0] += qi0 * ki0; k2v[0][1] += qi0 * ki1;
      k2v[1][0] += qi1 * ki0; k2v[1][1] += qi1 * ki1;
      kxv[0][0] += qr0 * ki0 + qi0 * kr0; kxv[0][1] += qr0 * ki1 + qi0 * kr1;
      kxv[1][0] += qr1 * ki0 + qi1 * kr0; kxv[1][1] += qr1 * ki1 + qi1 * kr1;
    }

    float L[2][2];
#pragma unroll
    for (int a = 0; a < 2; a++) {
#pragma unroll
      for (int b = 0; b < 2; b++) {
        const float ar_ = (k1v[a][b] - k2v[a][b]) * scale;
        const float ai_ = kxv[a][b] * scale;
        const float arr = ar_ + eps * ai_;
        const float aii = ai_ - eps * ar_;
        const float mag = sqrtf(arr * arr + aii * aii + 1e-6f);
        float Lv = mag * cfac;
        const int gi = i0 + tr * 2 + a;
        const int gj = j0 + tc * 2 + b;
        if (gj > gi) Lv = -1e30f;
        L[a][b] = Lv;
      }
    }

    // ---- online softmax (16 lanes per row group share state) ----
    float mt0 = fmaxf(L[0][0], L[0][1]);
    float mt1 = fmaxf(L[1][0], L[1][1]);
#pragma unroll
    for (int off = 8; off >= 1; off >>= 1) {
      mt0 = fmaxf(mt0, __shfl_xor(mt0, off, 16));
      mt1 = fmaxf(mt1, __shfl_xor(mt1, off, 16));
    }
    const float mn0 = fmaxf(m0, mt0), mn1 = fmaxf(m1, mt1);
    const float al0 = expf(m0 - mn0), al1 = expf(m1 - mn1);
    m0 = mn0; m1 = mn1;

    const float p00 = expf(L[0][0] - mn0), p01 = expf(L[0][1] - mn0);
    const float p10 = expf(L[1][0] - mn1), p11 = expf(L[1][1] - mn1);
    P_s[r0][c0] = p00; P_s[r0][c1] = p01;
    P_s[r1][c0] = p10; P_s[r1][c1] = p11;

    float rs0 = p00 + p01, rs1 = p10 + p11;
#pragma unroll
    for (int off = 8; off >= 1; off >>= 1) {
      rs0 += __shfl_xor(rs0, off, 16);
      rs1 += __shfl_xor(rs1, off, 16);
    }
    l0 = l0 * al0 + rs0;
    l1 = l1 * al1 + rs1;
#pragma unroll
    for (int cc = 0; cc < 4; cc++) {
      aR0[cc] *= al0; aI0[cc] *= al0;
      aR1[cc] *= al1; aI1[cc] *= al1;
    }
    __syncthreads();   // P_s fully written

    // ---- PV ----
    for (int j = 0; j < BN; j++) {
      const float pa = P_s[r0][j], pb = P_s[r1][j];
#pragma unroll
      for (int cc = 0; cc < 4; cc++) {
        const float vr = Vr_s[j][tc * 4 + cc];
        const float vi = Vi_s[j][tc * 4 + cc];
        aR0[cc] += pa * vr; aR1[cc] += pb * vr;
        aI0[cc] += pa * vi; aI1[cc] += pb * vi;
      }
    }
  }

  const float inv0 = 1.f / l0, inv1 = 1.f / l1;
#pragma unroll
  for (int cc = 0; cc < 4; cc++) {
    const int col = h * HD + tc * 4 + cc;
    Or[(size_t)(i0 + r0) * DIM + col] = aR0[cc] * inv0;
    Or[(size_t)(i0 + r1) * DIM + col] = aR1[cc] * inv1;
    Oi[(size_t)(i0 + r0) * DIM + col] = aI0[cc] * inv0;
    Oi[(size_t)(i0 + r1) * DIM + col] = aI1[cc] * inv1;
  }
}

// ---------------------------------------------------------------------------
extern "C" void kernel_launch(void* const* d_in, const int* in_sizes, int n_in,
                              void* d_out, int out_size, void* d_ws, size_t ws_size,
                              hipStream_t stream)
{
  const float* real = (const float*)d_in[0];
  const float* imag = (const float*)d_in[1];
  const float* Wq_r = (const float*)d_in[2];
  const float* bq_r = (const float*)d_in[3];
  const float* Wk_r = (const float*)d_in[4];
  const float* bk_r = (const float*)d_in[5];
  const float* Wv_r = (const float*)d_in[6];
  const float* bv_r = (const float*)d_in[7];
  const float* Wq_i = (const float*)d_in[8];
  const float* bq_i = (const float*)d_in[9];
  const float* Wk_i = (const float*)d_in[10];
  const float* bk_i = (const float*)d_in[11];
  const float* Wv_i = (const float*)d_in[12];
  const float* bv_i = (const float*)d_in[13];
  const float* Wo_r = (const float*)d_in[14];
  const float* bo_r = (const float*)d_in[15];
  const float* Wo_i = (const float*)d_in[16];
  const float* bo_i = (const float*)d_in[17];
  const float* phase = (const float*)d_in[18];
  const float* ent   = (const float*)d_in[19];
  const float* freqs = (const float*)d_in[20];
  const float* p_is  = (const float*)d_in[21];
  const float* p_at  = (const float*)d_in[22];
  const float* p_ce  = (const float*)d_in[23];

  float* ws = (float*)d_ws;
  const size_t SL = (size_t)S_LEN * DIM;   // 2,097,152 floats = 8 MB

  float* q_r = ws + 0 * SL;
  float* k_r = ws + 1 * SL;
  float* v_r = ws + 2 * SL;
  float* q_i = ws + 3 * SL;
  float* k_i = ws + 4 * SL;
  float* v_i = ws + 5 * SL;
  float* Qr  = ws + 6 * SL;
  float* Qi  = ws + 7 * SL;
  float* Kr  = ws + 8 * SL;
  float* Ki  = ws + 9 * SL;
  float* O_r = q_r;   // q_r/q_i dead after entangle
  float* O_i = q_i;

  float* out_r = (float*)d_out;
  float* out_i = out_r + SL;

  // 1. six input projections -> head-major [h][s][d]
  GemmBatch g1;
  g1.A[0] = real; g1.A[1] = real; g1.A[2] = real;
  g1.A[3] = imag; g1.A[4] = imag; g1.A[5] = imag;
  g1.W[0] = Wq_r; g1.W[1] = Wk_r; g1.W[2] = Wv_r;
  g1.W[3] = Wq_i; g1.W[4] = Wk_i; g1.W[5] = Wv_i;
  g1.bias[0] = bq_r; g1.bias[1] = bk_r; g1.bias[2] = bv_r;
  g1.bias[3] = bq_i; g1.bias[4] = bk_i; g1.bias[5] = bv_i;
  g1.C[0] = q_r; g1.C[1] = k_r; g1.C[2] = v_r;
  g1.C[3] = q_i; g1.C[4] = k_i; g1.C[5] = v_i;
  gemm_bias_kernel<<<dim3(16, 32, 6), dim3(256), 0, stream>>>(g1, 1);

  // 2. RoPE in-place on q_r, k_r, q_i, k_i
  rope_kernel<<<dim3(8192), dim3(256), 0, stream>>>(q_r, k_r, q_i, k_i, freqs);

  // 3. entangle + phase: q_r,q_i -> Qr,Qi ; k_r,k_i -> Kr,Ki
  entangle_kernel<<<dim3(512, 1, 2), dim3(256), 0, stream>>>(
      q_r, q_i, Qr, Qi, k_r, k_i, Kr, Ki, ent, phase);

  // 4. flash attention -> O row-major (s, DIM)
  flash_kernel<<<dim3(S_LEN / 32, NH), dim3(256), 0, stream>>>(
      Qr, Qi, Kr, Ki, v_r, v_i, O_r, O_i, p_is, p_at, p_ce);

  // 5. output projections -> d_out (out_r then out_i)
  GemmBatch g2 = {};
  g2.A[0] = O_r; g2.A[1] = O_i;
  g2.W[0] = Wo_r; g2.W[1] = Wo_i;
  g2.bias[0] = bo_r; g2.bias[1] = bo_i;
  g2.C[0] = out_r; g2.C[1] = out_i;
  gemm_bias_kernel<<<dim3(16, 32, 2), dim3(256), 0, stream>>>(g2, 0);
}

// Round 2
// 1021.968 us; speedup vs baseline: 2.0475x; 2.0475x over previous
//
#include <hip/hip_runtime.h>
#include <cstddef>
#include <cstdint>
#include <math.h>

#define S_LEN 2048
#define DIM 1024
#define NH 16
#define HD 64
#define NFREQ 16

typedef __attribute__((ext_vector_type(8))) short bf16x8;
typedef __attribute__((ext_vector_type(4))) float f32x4;

__device__ inline unsigned short f2bf(float x) {
  union { float f; unsigned u; } v; v.f = x;
  unsigned r = v.u + 0x7FFFu + ((v.u >> 16) & 1u);   // round-to-nearest-even
  return (unsigned short)(r >> 16);
}

// ---------------------------------------------------------------------------
// GEMM: C = A @ W^T + bias.  A: (2048,1024) row-major, W: (1024,1024) row-major.
// mode 0: C row-major (s, DIM).  mode 1: C head-major [h][s][d].
// ---------------------------------------------------------------------------
struct GemmBatch {
  const float* A[6];
  const float* W[6];
  const float* bias[6];
  float* C[6];
};

__global__ __launch_bounds__(256) void gemm_bias_kernel(GemmBatch gb, int mode)
{
  const int z = blockIdx.z;
  const float* __restrict__ A = gb.A[z];
  const float* __restrict__ W = gb.W[z];
  const float* __restrict__ bias = gb.bias[z];
  float* __restrict__ C = gb.C[z];
  const int K = DIM;

  __shared__ float As[16][65];
  __shared__ float Bs[16][65];

  const int t  = threadIdx.x;
  const int tr = t >> 4;
  const int tc = t & 15;
  const int m0 = blockIdx.y * 64;
  const int n0 = blockIdx.x * 64;
  const int lm = t >> 4;
  const int lk = t & 15;

  float acc[4][4] = {};

  for (int k0 = 0; k0 < K; k0 += 16) {
#pragma unroll
    for (int q = 0; q < 4; q++) {
      As[lk][lm + 16*q] = A[(size_t)(m0 + lm + 16*q) * K + (k0 + lk)];
      Bs[lk][lm + 16*q] = W[(size_t)(n0 + lm + 16*q) * K + (k0 + lk)];
    }
    __syncthreads();
#pragma unroll
    for (int kk = 0; kk < 16; kk++) {
      float a[4], b[4];
#pragma unroll
      for (int i = 0; i < 4; i++) a[i] = As[kk][tr*4 + i];
#pragma unroll
      for (int j = 0; j < 4; j++) b[j] = Bs[kk][tc*4 + j];
#pragma unroll
      for (int i = 0; i < 4; i++)
#pragma unroll
        for (int j = 0; j < 4; j++)
          acc[i][j] += a[i] * b[j];
    }
    __syncthreads();
  }

#pragma unroll
  for (int i = 0; i < 4; i++) {
    const int m = m0 + tr*4 + i;
#pragma unroll
    for (int j = 0; j < 4; j++) {
      const int n = n0 + tc*4 + j;
      const float v = acc[i][j] + bias[n];
      if (mode == 0) {
        C[(size_t)m * DIM + n] = v;
      } else {
        const int hh = n >> 6, d = n & 63;
        C[((size_t)hh * S_LEN + m) * HD + d] = v;
      }
    }
  }
}

// ---------------------------------------------------------------------------
// RoPE (interleaved) on first 32 dims of each head, in-place on 4 tensors.
// ---------------------------------------------------------------------------
__global__ __launch_bounds__(256) void rope_kernel(
    float* q_r, float* k_r, float* q_i, float* k_i,
    const float* __restrict__ freqs)
{
  const int gid = blockIdx.x * 256 + threadIdx.x;
  const int j  = gid & 15;
  const int s  = (gid >> 4) & (S_LEN - 1);
  const int h  = (gid >> 15) & (NH - 1);
  const int tz = gid >> 19;
  float* buf = (tz == 0) ? q_r : (tz == 1) ? k_r : (tz == 2) ? q_i : k_i;

  const float ang = (float)s * freqs[j];
  float sn, cs;
  sincosf(ang, &sn, &cs);

  const size_t base = ((size_t)h * S_LEN + s) * HD + 2*j;
  const float x1 = buf[base];
  const float x2 = buf[base + 1];
  buf[base]     = x1 * cs - x2 * sn;
  buf[base + 1] = x1 * sn + x2 * cs;
}

// ---------------------------------------------------------------------------
// Entanglement (head mix) + phase rotation.
// ---------------------------------------------------------------------------
__global__ __launch_bounds__(256) void entangle_kernel(
    const float* __restrict__ qr_in, const float* __restrict__ qi_in,
    float* __restrict__ qr_out, float* __restrict__ qi_out,
    const float* __restrict__ kr_in, const float* __restrict__ ki_in,
    float* __restrict__ kr_out, float* __restrict__ ki_out,
    const float* __restrict__ E, const float* __restrict__ phase)
{
  const int z = blockIdx.z;
  const float* inR = z ? kr_in : qr_in;
  const float* inI = z ? ki_in : qi_in;
  float* outR = z ? kr_out : qr_out;
  float* outI = z ? ki_out : qi_out;

  __shared__ float Es[NH * NH];
  const int t = threadIdx.x;
  Es[t] = E[t];
  __syncthreads();

  const int idx = blockIdx.x * 256 + t;
  const int s = idx >> 6;
  const int d = idx & 63;

  float vr[NH], vi[NH];
#pragma unroll
  for (int h = 0; h < NH; h++) {
    const size_t off = ((size_t)h * S_LEN + s) * HD + d;
    vr[h] = inR[off];
    vi[h] = inI[off];
  }

#pragma unroll
  for (int x = 0; x < NH; x++) {
    float er = 0.f, ei = 0.f;
#pragma unroll
    for (int h = 0; h < NH; h++) {
      const float e = Es[h * NH + x];
      er += vr[h] * e;
      ei += vi[h] * e;
    }
    const float ph = phase[x * HD + d];
    float ps, pc;
    sincosf(ph, &ps, &pc);
    const size_t off = ((size_t)x * S_LEN + s) * HD + d;
    outR[off] = er * pc - ei * ps;
    outI[off] = er * ps + ei * pc;
  }
}

// ---------------------------------------------------------------------------
// Flash attention on MFMA (bf16 16x16x32).
// BM=BN=64, 4 waves; wave w owns Q rows [w*16, w*16+16).
// Layouts (gfx950 verified): A-frag A[m=lane&15][k=quad*8+j],
// B-frag B[k=quad*8+j][n=lane&15], C/D row=quad*4+reg, col=lane&15.
// Q frags loaded from global directly into registers (once per block).
// K staged in LDS [kv][d] bf16; V staged TRANSPOSED [d][kv] bf16 so both
// score-B and PV-B frags are contiguous ds_read_b128.
// P goes through LDS [m][kv] (rows are wave-private -> no extra barrier).
// ---------------------------------------------------------------------------
#define LDK 72   // bf16 elements per row: 144 B = multiple of 16 B, breaks 2^k strides

__global__ __launch_bounds__(256) void flash_mfma_kernel(
    const float* __restrict__ Qr, const float* __restrict__ Qi,
    const float* __restrict__ Kr, const float* __restrict__ Ki,
    const float* __restrict__ Vr, const float* __restrict__ Vi,
    float* __restrict__ Or, float* __restrict__ Oi,
    const float* __restrict__ p_is, const float* __restrict__ p_at,
    const float* __restrict__ p_ce)
{
  __shared__ __align__(16) unsigned short Krs[64*LDK];
  __shared__ __align__(16) unsigned short Kis[64*LDK];
  __shared__ __align__(16) unsigned short VTr[64*LDK];
  __shared__ __align__(16) unsigned short VTi[64*LDK];
  __shared__ __align__(16) unsigned short Ps [64*LDK];

  const int t    = threadIdx.x;
  const int lane = t & 63;
  const int w    = t >> 6;       // wave 0..3
  const int quad = lane >> 4;    // 0..3
  const int lcol = lane & 15;    // 0..15
  const int h    = blockIdx.y;
  const int i0   = blockIdx.x * 64;

  const float strength = 1.f / (1.f + expf(-p_is[0]));
  const float temp     = fmaxf(expf(p_at[0]), 0.1f);
  const float cfac     = strength / temp;
  const float eps      = 0.03f / (1.f + expf(-p_ce[0]));
  const float scale    = 0.125f;   // 1/sqrt(64)

  // ---- Q fragments from global (fp32 -> bf16), once per block ----
  bf16x8 qrf[2], qif[2];
  {
    const int qrow = i0 + w*16 + lcol;
    const size_t base = ((size_t)h * S_LEN + qrow) * HD;
#pragma unroll
    for (int ks = 0; ks < 2; ks++) {
      const float* pr = Qr + base + ks*32 + quad*8;
      const float* pi = Qi + base + ks*32 + quad*8;
      float4 a0 = *(const float4*)pr;
      float4 a1 = *(const float4*)(pr + 4);
      float4 b0 = *(const float4*)pi;
      float4 b1 = *(const float4*)(pi + 4);
      bf16x8 qa, qb;
      qa[0]=(short)f2bf(a0.x); qa[1]=(short)f2bf(a0.y); qa[2]=(short)f2bf(a0.z); qa[3]=(short)f2bf(a0.w);
      qa[4]=(short)f2bf(a1.x); qa[5]=(short)f2bf(a1.y); qa[6]=(short)f2bf(a1.z); qa[7]=(short)f2bf(a1.w);
      qb[0]=(short)f2bf(b0.x); qb[1]=(short)f2bf(b0.y); qb[2]=(short)f2bf(b0.z); qb[3]=(short)f2bf(b0.w);
      qb[4]=(short)f2bf(b1.x); qb[5]=(short)f2bf(b1.y); qb[6]=(short)f2bf(b1.z); qb[7]=(short)f2bf(b1.w);
      qrf[ks] = qa;
      qif[ks] = qb;
    }
  }

  float m_i[4], l_i[4];
  f32x4 aOr[4], aOi[4];
#pragma unroll
  for (int r = 0; r < 4; r++) { m_i[r] = -1e30f; l_i[r] = 0.f; }
#pragma unroll
  for (int c = 0; c < 4; c++) {
#pragma unroll
    for (int r = 0; r < 4; r++) { aOr[c][r] = 0.f; aOi[c][r] = 0.f; }
  }

  const int ntiles = (i0 >> 6) + 1;
  for (int jt = 0; jt < ntiles; jt++) {
    const int j0 = jt * 64;

    __syncthreads();   // all waves done with previous K/V (and P re-written later)

    // ---- stage K [kv][d] and V^T [d][kv] as bf16 ----
    const size_t kb = ((size_t)h * S_LEN + j0) * HD;
#pragma unroll
    for (int it = 0; it < 4; it++) {
      const int idx = t + it * 256;        // 0..1023
      const int row = idx >> 4;            // kv row 0..63
      const int d0  = (idx & 15) * 4;      // d 0..60 step 4
      const size_t g = kb + (size_t)row * HD + d0;
      float4 kr4 = *(const float4*)(Kr + g);
      float4 ki4 = *(const float4*)(Ki + g);
      float4 vr4 = *(const float4*)(Vr + g);
      float4 vi4 = *(const float4*)(Vi + g);
      ushort4 kp, ip;
      kp.x = f2bf(kr4.x); kp.y = f2bf(kr4.y); kp.z = f2bf(kr4.z); kp.w = f2bf(kr4.w);
      ip.x = f2bf(ki4.x); ip.y = f2bf(ki4.y); ip.z = f2bf(ki4.z); ip.w = f2bf(ki4.w);
      *(ushort4*)&Krs[row*LDK + d0] = kp;
      *(ushort4*)&Kis[row*LDK + d0] = ip;
      VTr[(d0+0)*LDK + row] = f2bf(vr4.x);
      VTr[(d0+1)*LDK + row] = f2bf(vr4.y);
      VTr[(d0+2)*LDK + row] = f2bf(vr4.z);
      VTr[(d0+3)*LDK + row] = f2bf(vr4.w);
      VTi[(d0+0)*LDK + row] = f2bf(vi4.x);
      VTi[(d0+1)*LDK + row] = f2bf(vi4.y);
      VTi[(d0+2)*LDK + row] = f2bf(vi4.z);
      VTi[(d0+3)*LDK + row] = f2bf(vi4.w);
    }
    __syncthreads();

    // ---- scores: k1 = Qr.Kr^T, k2 = Qi.Ki^T, kx = Qr.Ki^T + Qi.Kr^T ----
    f32x4 k1[4], k2[4], kx[4];
#pragma unroll
    for (int c = 0; c < 4; c++) {
#pragma unroll
      for (int r = 0; r < 4; r++) { k1[c][r] = 0.f; k2[c][r] = 0.f; kx[c][r] = 0.f; }
    }
#pragma unroll
    for (int ks = 0; ks < 2; ks++) {
#pragma unroll
      for (int c = 0; c < 4; c++) {
        const int off = (c*16 + lcol)*LDK + ks*32 + quad*8;
        bf16x8 krf = *(const bf16x8*)&Krs[off];
        bf16x8 kif = *(const bf16x8*)&Kis[off];
        k1[c] = __builtin_amdgcn_mfma_f32_16x16x32_bf16(qrf[ks], krf, k1[c], 0, 0, 0);
        k2[c] = __builtin_amdgcn_mfma_f32_16x16x32_bf16(qif[ks], kif, k2[c], 0, 0, 0);
        kx[c] = __builtin_amdgcn_mfma_f32_16x16x32_bf16(qrf[ks], kif, kx[c], 0, 0, 0);
        kx[c] = __builtin_amdgcn_mfma_f32_16x16x32_bf16(qif[ks], krf, kx[c], 0, 0, 0);
      }
    }

    // ---- magnitude logits + online softmax (per C-layout row) ----
    const bool diag = (jt == ntiles - 1);
#pragma unroll
    for (int r = 0; r < 4; r++) {
      float Lv[4];
#pragma unroll
      for (int c = 0; c < 4; c++) {
        const float ar_ = (k1[c][r] - k2[c][r]) * scale;
        const float ai_ = kx[c][r] * scale;
        const float arr = ar_ + eps * ai_;
        const float aii = ai_ - eps * ar_;
        const float mag = sqrtf(arr*arr + aii*aii + 1e-6f);
        float L = mag * cfac;
        if (diag) {
          const int gi = i0 + w*16 + quad*4 + r;
          const int gj = j0 + c*16 + lcol;
          if (gj > gi) L = -1e30f;
        }
        Lv[c] = L;
      }
      float mt = fmaxf(fmaxf(Lv[0], Lv[1]), fmaxf(Lv[2], Lv[3]));
#pragma unroll
      for (int off = 1; off < 16; off <<= 1)
        mt = fmaxf(mt, __shfl_xor(mt, off, 64));
      const float mn = fmaxf(m_i[r], mt);
      const float al = __expf(m_i[r] - mn);
      m_i[r] = mn;
      float rs = 0.f;
      const int prow = (w*16 + quad*4 + r) * LDK;
#pragma unroll
      for (int c = 0; c < 4; c++) {
        const float p = __expf(Lv[c] - mn);
        Ps[prow + c*16 + lcol] = f2bf(p);
        rs += p;
      }
#pragma unroll
      for (int off = 1; off < 16; off <<= 1)
        rs += __shfl_xor(rs, off, 64);
      l_i[r] = l_i[r] * al + rs;
#pragma unroll
      for (int c = 0; c < 4; c++) { aOr[c][r] *= al; aOi[c][r] *= al; }
    }

    // ---- PV: O += P @ V (P rows are wave-private; lgkmcnt handles the
    //      intra-wave LDS write->read dependency, no barrier needed) ----
#pragma unroll
    for (int ks = 0; ks < 2; ks++) {
      bf16x8 pf = *(const bf16x8*)&Ps[(w*16 + lcol)*LDK + ks*32 + quad*8];
#pragma unroll
      for (int c = 0; c < 4; c++) {
        const int off = (c*16 + lcol)*LDK + ks*32 + quad*8;
        bf16x8 vrf = *(const bf16x8*)&VTr[off];
        bf16x8 vif = *(const bf16x8*)&VTi[off];
        aOr[c] = __builtin_amdgcn_mfma_f32_16x16x32_bf16(pf, vrf, aOr[c], 0, 0, 0);
        aOi[c] = __builtin_amdgcn_mfma_f32_16x16x32_bf16(pf, vif, aOi[c], 0, 0, 0);
      }
    }
  }

  // ---- epilogue: normalize and write row-major (s, DIM) ----
  float inv[4];
#pragma unroll
  for (int r = 0; r < 4; r++) inv[r] = 1.f / l_i[r];
#pragma unroll
  for (int c = 0; c < 4; c++) {
#pragma unroll
    for (int r = 0; r < 4; r++) {
      const int row = i0 + w*16 + quad*4 + r;
      const int col = h*HD + c*16 + lcol;
      Or[(size_t)row * DIM + col] = aOr[c][r] * inv[r];
      Oi[(size_t)row * DIM + col] = aOi[c][r] * inv[r];
    }
  }
}

// ---------------------------------------------------------------------------
extern "C" void kernel_launch(void* const* d_in, const int* in_sizes, int n_in,
                              void* d_out, int out_size, void* d_ws, size_t ws_size,
                              hipStream_t stream)
{
  const float* real = (const float*)d_in[0];
  const float* imag = (const float*)d_in[1];
  const float* Wq_r = (const float*)d_in[2];
  const float* bq_r = (const float*)d_in[3];
  const float* Wk_r = (const float*)d_in[4];
  const float* bk_r = (const float*)d_in[5];
  const float* Wv_r = (const float*)d_in[6];
  const float* bv_r = (const float*)d_in[7];
  const float* Wq_i = (const float*)d_in[8];
  const float* bq_i = (const float*)d_in[9];
  const float* Wk_i = (const float*)d_in[10];
  const float* bk_i = (const float*)d_in[11];
  const float* Wv_i = (const float*)d_in[12];
  const float* bv_i = (const float*)d_in[13];
  const float* Wo_r = (const float*)d_in[14];
  const float* bo_r = (const float*)d_in[15];
  const float* Wo_i = (const float*)d_in[16];
  const float* bo_i = (const float*)d_in[17];
  const float* phase = (const float*)d_in[18];
  const float* ent   = (const float*)d_in[19];
  const float* freqs = (const float*)d_in[20];
  const float* p_is  = (const float*)d_in[21];
  const float* p_at  = (const float*)d_in[22];
  const float* p_ce  = (const float*)d_in[23];

  float* ws = (float*)d_ws;
  const size_t SL = (size_t)S_LEN * DIM;

  float* q_r = ws + 0 * SL;
  float* k_r = ws + 1 * SL;
  float* v_r = ws + 2 * SL;
  float* q_i = ws + 3 * SL;
  float* k_i = ws + 4 * SL;
  float* v_i = ws + 5 * SL;
  float* Qr  = ws + 6 * SL;
  float* Qi  = ws + 7 * SL;
  float* Kr  = ws + 8 * SL;
  float* Ki  = ws + 9 * SL;
  float* O_r = q_r;   // q_r/q_i dead after entangle
  float* O_i = q_i;

  float* out_r = (float*)d_out;
  float* out_i = out_r + SL;

  // 1. six input projections -> head-major [h][s][d]
  GemmBatch g1;
  g1.A[0] = real; g1.A[1] = real; g1.A[2] = real;
  g1.A[3] = imag; g1.A[4] = imag; g1.A[5] = imag;
  g1.W[0] = Wq_r; g1.W[1] = Wk_r; g1.W[2] = Wv_r;
  g1.W[3] = Wq_i; g1.W[4] = Wk_i; g1.W[5] = Wv_i;
  g1.bias[0] = bq_r; g1.bias[1] = bk_r; g1.bias[2] = bv_r;
  g1.bias[3] = bq_i; g1.bias[4] = bk_i; g1.bias[5] = bv_i;
  g1.C[0] = q_r; g1.C[1] = k_r; g1.C[2] = v_r;
  g1.C[3] = q_i; g1.C[4] = k_i; g1.C[5] = v_i;
  gemm_bias_kernel<<<dim3(16, 32, 6), dim3(256), 0, stream>>>(g1, 1);

  // 2. RoPE in-place on q_r, k_r, q_i, k_i
  rope_kernel<<<dim3(8192), dim3(256), 0, stream>>>(q_r, k_r, q_i, k_i, freqs);

  // 3. entangle + phase: q_r,q_i -> Qr,Qi ; k_r,k_i -> Kr,Ki
  entangle_kernel<<<dim3(512, 1, 2), dim3(256), 0, stream>>>(
      q_r, q_i, Qr, Qi, k_r, k_i, Kr, Ki, ent, phase);

  // 4. flash attention (MFMA) -> O row-major (s, DIM)
  flash_mfma_kernel<<<dim3(S_LEN / 64, NH), dim3(256), 0, stream>>>(
      Qr, Qi, Kr, Ki, v_r, v_i, O_r, O_i, p_is, p_at, p_ce);

  // 5. output projections -> d_out (out_r then out_i)
  GemmBatch g2 = {};
  g2.A[0] = O_r; g2.A[1] = O_i;
  g2.W[0] = Wo_r; g2.W[1] = Wo_i;
  g2.bias[0] = bo_r; g2.bias[1] = bo_i;
  g2.C[0] = out_r; g2.C[1] = out_i;
  gemm_bias_kernel<<<dim3(16, 32, 2), dim3(256), 0, stream>>>(g2, 0);
}

// Round 3
// 450.681 us; speedup vs baseline: 4.6429x; 2.2676x over previous
//
#include <hip/hip_runtime.h>
#include <cstddef>
#include <cstdint>
#include <math.h>

#define S_LEN 2048
#define DIM 1024
#define NH 16
#define HD 64

typedef __attribute__((ext_vector_type(8))) short bf16x8;
typedef __attribute__((ext_vector_type(8))) unsigned short u16x8;
typedef __attribute__((ext_vector_type(4))) float f32x4;

__device__ inline unsigned short f2bf(float x) {
  union { float f; unsigned u; } v; v.f = x;
  unsigned r = v.u + 0x7FFFu + ((v.u >> 16) & 1u);   // round-to-nearest-even
  return (unsigned short)(r >> 16);
}
__device__ inline float bf2f(unsigned short x) {
  union { unsigned u; float f; } v; v.u = ((unsigned)x) << 16; return v.f;
}

#define GLOAD_LDS16(g, l)                                              \
  __builtin_amdgcn_global_load_lds(                                    \
      (const __attribute__((address_space(1))) void*)(g),              \
      (__attribute__((address_space(3))) void*)(l), 16, 0, 0)

// ---------------------------------------------------------------------------
// fp32 -> bf16 conversion for 10 tensors (real, imag, 6x W, 2x Wo).
// ---------------------------------------------------------------------------
struct ConvBatch {
  const float* src[10];
  unsigned short* dst[10];
  int n[10];
};

__global__ __launch_bounds__(256) void conv_kernel(ConvBatch cb)
{
  const int y = blockIdx.y;
  const int i = (blockIdx.x * 256 + threadIdx.x) * 8;
  if (i >= cb.n[y]) return;
  const float* s = cb.src[y];
  float4 a = *(const float4*)(s + i);
  float4 b = *(const float4*)(s + i + 4);
  u16x8 o;
  o[0] = f2bf(a.x); o[1] = f2bf(a.y); o[2] = f2bf(a.z); o[3] = f2bf(a.w);
  o[4] = f2bf(b.x); o[5] = f2bf(b.y); o[6] = f2bf(b.z); o[7] = f2bf(b.w);
  *(u16x8*)(cb.dst[y] + i) = o;
}

// ---------------------------------------------------------------------------
// bf16 MFMA GEMM: C = A @ W^T + bias.  A: (2048,1024) bf16 row-major,
// W: (1024,1024) bf16 row-major (so both are K-contiguous).
// m97 structure: 128x128 tile, BK=32, unpadded LDS, global_load_lds w=16,
// 2-barrier K-loop. 4 waves in 2x2; each wave 64x64 via 4x4 16x16x32 frags.
// mode 0: C fp32 row-major (s, DIM).  mode 1: C bf16 head-major [h][s][d].
// ---------------------------------------------------------------------------
struct BGemm {
  const unsigned short* A[6];
  const unsigned short* W[6];
  const float* bias[6];
  void* C[6];
};

__global__ __launch_bounds__(256) void gemm_mfma_kernel(BGemm gb, int mode)
{
  constexpr int K = DIM;
  const int z = blockIdx.z;
  const unsigned short* __restrict__ A = gb.A[z];
  const unsigned short* __restrict__ W = gb.W[z];
  const float* __restrict__ bias = gb.bias[z];

  __shared__ __align__(16) unsigned short As[128 * 32];
  __shared__ __align__(16) unsigned short Ws[128 * 32];

  const int t    = threadIdx.x;
  const int lane = t & 63;
  const int w    = t >> 6;
  const int wm   = w >> 1, wn = w & 1;
  const int quad = lane >> 4, lcol = lane & 15;
  const int m0   = blockIdx.y * 128;
  const int n0   = blockIdx.x * 128;

  const int srow = t >> 2;         // 0..63 (+ pass*64)
  const int sk8  = (t & 3) * 8;

  f32x4 acc[4][4];
#pragma unroll
  for (int i = 0; i < 4; i++)
#pragma unroll
    for (int j = 0; j < 4; j++)
#pragma unroll
      for (int r = 0; r < 4; r++) acc[i][j][r] = 0.f;

  for (int k0 = 0; k0 < K; k0 += 32) {
    __syncthreads();   // previous tile's ds_reads done
#pragma unroll
    for (int p = 0; p < 2; p++) {
      const unsigned short* ga = A + (size_t)(m0 + p * 64 + srow) * K + k0 + sk8;
      GLOAD_LDS16(ga, As + (size_t)(p * 256 + w * 64) * 8);
      const unsigned short* gw = W + (size_t)(n0 + p * 64 + srow) * K + k0 + sk8;
      GLOAD_LDS16(gw, Ws + (size_t)(p * 256 + w * 64) * 8);
    }
    __syncthreads();   // drains vmcnt -> LDS tiles ready

    bf16x8 af[4], bf[4];
#pragma unroll
    for (int mi = 0; mi < 4; mi++)
      af[mi] = *(const bf16x8*)&As[(wm * 64 + mi * 16 + lcol) * 32 + quad * 8];
#pragma unroll
    for (int ni = 0; ni < 4; ni++)
      bf[ni] = *(const bf16x8*)&Ws[(wn * 64 + ni * 16 + lcol) * 32 + quad * 8];
#pragma unroll
    for (int mi = 0; mi < 4; mi++)
#pragma unroll
      for (int ni = 0; ni < 4; ni++)
        acc[mi][ni] = __builtin_amdgcn_mfma_f32_16x16x32_bf16(af[mi], bf[ni], acc[mi][ni], 0, 0, 0);
  }

#pragma unroll
  for (int mi = 0; mi < 4; mi++) {
#pragma unroll
    for (int ni = 0; ni < 4; ni++) {
#pragma unroll
      for (int r = 0; r < 4; r++) {
        const int grow = m0 + wm * 64 + mi * 16 + quad * 4 + r;
        const int gcol = n0 + wn * 64 + ni * 16 + lcol;
        const float v = acc[mi][ni][r] + bias[gcol];
        if (mode == 0) {
          ((float*)gb.C[z])[(size_t)grow * DIM + gcol] = v;
        } else {
          const int hh = gcol >> 6, d = gcol & 63;
          ((unsigned short*)gb.C[z])[((size_t)hh * S_LEN + grow) * HD + d] = f2bf(v);
        }
      }
    }
  }
}

// ---------------------------------------------------------------------------
// RoPE (interleaved) on first 32 dims of each head, in-place, bf16.
// ---------------------------------------------------------------------------
__global__ __launch_bounds__(256) void rope_kernel(
    unsigned short* q_r, unsigned short* k_r,
    unsigned short* q_i, unsigned short* k_i,
    const float* __restrict__ freqs)
{
  const int gid = blockIdx.x * 256 + threadIdx.x;
  const int j  = gid & 15;
  const int s  = (gid >> 4) & (S_LEN - 1);
  const int h  = (gid >> 15) & (NH - 1);
  const int tz = gid >> 19;
  unsigned short* buf = (tz == 0) ? q_r : (tz == 1) ? k_r : (tz == 2) ? q_i : k_i;

  const float ang = (float)s * freqs[j];
  float sn, cs;
  sincosf(ang, &sn, &cs);

  const size_t base = ((size_t)h * S_LEN + s) * HD + 2 * j;
  ushort2 xv = *(const ushort2*)(buf + base);
  const float x1 = bf2f(xv.x), x2 = bf2f(xv.y);
  ushort2 ov;
  ov.x = f2bf(x1 * cs - x2 * sn);
  ov.y = f2bf(x1 * sn + x2 * cs);
  *(ushort2*)(buf + base) = ov;
}

// ---------------------------------------------------------------------------
// Entanglement (head mix) + phase rotation, bf16 in/out, fp32 math.
// ---------------------------------------------------------------------------
__global__ __launch_bounds__(256) void entangle_kernel(
    const unsigned short* __restrict__ qr_in, const unsigned short* __restrict__ qi_in,
    unsigned short* __restrict__ qr_out, unsigned short* __restrict__ qi_out,
    const unsigned short* __restrict__ kr_in, const unsigned short* __restrict__ ki_in,
    unsigned short* __restrict__ kr_out, unsigned short* __restrict__ ki_out,
    const float* __restrict__ E, const float* __restrict__ phase)
{
  const int z = blockIdx.z;
  const unsigned short* inR = z ? kr_in : qr_in;
  const unsigned short* inI = z ? ki_in : qi_in;
  unsigned short* outR = z ? kr_out : qr_out;
  unsigned short* outI = z ? ki_out : qi_out;

  __shared__ float Es[NH * NH];
  const int t = threadIdx.x;
  Es[t] = E[t];
  __syncthreads();

  const int idx = blockIdx.x * 256 + t;
  const int s = idx >> 6;
  const int d = idx & 63;

  float vr[NH], vi[NH];
#pragma unroll
  for (int h = 0; h < NH; h++) {
    const size_t off = ((size_t)h * S_LEN + s) * HD + d;
    vr[h] = bf2f(inR[off]);
    vi[h] = bf2f(inI[off]);
  }

#pragma unroll
  for (int x = 0; x < NH; x++) {
    float er = 0.f, ei = 0.f;
#pragma unroll
    for (int h = 0; h < NH; h++) {
      const float e = Es[h * NH + x];
      er += vr[h] * e;
      ei += vi[h] * e;
    }
    const float ph = phase[x * HD + d];
    float ps, pc;
    sincosf(ph, &ps, &pc);
    const size_t off = ((size_t)x * S_LEN + s) * HD + d;
    outR[off] = f2bf(er * pc - ei * ps);
    outI[off] = f2bf(er * ps + ei * pc);
  }
}

// ---------------------------------------------------------------------------
// Flash attention on MFMA (bf16 16x16x32), bf16 inputs AND outputs.
// BM=BN=64, 4 waves; wave w owns Q rows [w*16, w*16+16).
// K staged [kv][d], V staged transposed [d][kv], P via LDS [m][kv].
// ---------------------------------------------------------------------------
#define LDK 72   // 144 B row stride: multiple of 16 B, breaks 2^k strides

__global__ __launch_bounds__(256) void flash_mfma_kernel(
    const unsigned short* __restrict__ Qr, const unsigned short* __restrict__ Qi,
    const unsigned short* __restrict__ Kr, const unsigned short* __restrict__ Ki,
    const unsigned short* __restrict__ Vr, const unsigned short* __restrict__ Vi,
    unsigned short* __restrict__ Or, unsigned short* __restrict__ Oi,
    const float* __restrict__ p_is, const float* __restrict__ p_at,
    const float* __restrict__ p_ce)
{
  __shared__ __align__(16) unsigned short Krs[64 * LDK];
  __shared__ __align__(16) unsigned short Kis[64 * LDK];
  __shared__ __align__(16) unsigned short VTr[64 * LDK];
  __shared__ __align__(16) unsigned short VTi[64 * LDK];
  __shared__ __align__(16) unsigned short Ps [64 * LDK];

  const int t    = threadIdx.x;
  const int lane = t & 63;
  const int w    = t >> 6;
  const int quad = lane >> 4;
  const int lcol = lane & 15;
  const int h    = blockIdx.y;
  const int i0   = blockIdx.x * 64;

  const float strength = 1.f / (1.f + expf(-p_is[0]));
  const float temp     = fmaxf(expf(p_at[0]), 0.1f);
  const float cfac     = strength / temp;
  const float eps      = 0.03f / (1.f + expf(-p_ce[0]));
  const float scale    = 0.125f;

  // Q fragments straight from global bf16
  bf16x8 qrf[2], qif[2];
  {
    const int qrow = i0 + w * 16 + lcol;
    const size_t base = ((size_t)h * S_LEN + qrow) * HD;
#pragma unroll
    for (int ks = 0; ks < 2; ks++) {
      qrf[ks] = *(const bf16x8*)(Qr + base + ks * 32 + quad * 8);
      qif[ks] = *(const bf16x8*)(Qi + base + ks * 32 + quad * 8);
    }
  }

  float m_i[4], l_i[4];
  f32x4 aOr[4], aOi[4];
#pragma unroll
  for (int r = 0; r < 4; r++) { m_i[r] = -1e30f; l_i[r] = 0.f; }
#pragma unroll
  for (int c = 0; c < 4; c++)
#pragma unroll
    for (int r = 0; r < 4; r++) { aOr[c][r] = 0.f; aOi[c][r] = 0.f; }

  const int ntiles = (i0 >> 6) + 1;
  for (int jt = 0; jt < ntiles; jt++) {
    const int j0 = jt * 64;

    __syncthreads();

    // stage K [kv][d] and V^T [d][kv]
    const size_t kb = ((size_t)h * S_LEN + j0) * HD;
#pragma unroll
    for (int it = 0; it < 2; it++) {
      const int idx = t + it * 256;        // 0..511
      const int row = idx >> 3;            // 0..63
      const int d0  = (idx & 7) * 8;       // 0..56 step 8
      const size_t g = kb + (size_t)row * HD + d0;
      bf16x8 kr8 = *(const bf16x8*)(Kr + g);
      bf16x8 ki8 = *(const bf16x8*)(Ki + g);
      bf16x8 vr8 = *(const bf16x8*)(Vr + g);
      bf16x8 vi8 = *(const bf16x8*)(Vi + g);
      *(bf16x8*)&Krs[row * LDK + d0] = kr8;
      *(bf16x8*)&Kis[row * LDK + d0] = ki8;
#pragma unroll
      for (int jj = 0; jj < 8; jj++) {
        VTr[(d0 + jj) * LDK + row] = (unsigned short)vr8[jj];
        VTi[(d0 + jj) * LDK + row] = (unsigned short)vi8[jj];
      }
    }
    __syncthreads();

    // scores
    f32x4 k1[4], k2[4], kx[4];
#pragma unroll
    for (int c = 0; c < 4; c++)
#pragma unroll
      for (int r = 0; r < 4; r++) { k1[c][r] = 0.f; k2[c][r] = 0.f; kx[c][r] = 0.f; }
#pragma unroll
    for (int ks = 0; ks < 2; ks++) {
#pragma unroll
      for (int c = 0; c < 4; c++) {
        const int off = (c * 16 + lcol) * LDK + ks * 32 + quad * 8;
        bf16x8 krf = *(const bf16x8*)&Krs[off];
        bf16x8 kif = *(const bf16x8*)&Kis[off];
        k1[c] = __builtin_amdgcn_mfma_f32_16x16x32_bf16(qrf[ks], krf, k1[c], 0, 0, 0);
        k2[c] = __builtin_amdgcn_mfma_f32_16x16x32_bf16(qif[ks], kif, k2[c], 0, 0, 0);
        kx[c] = __builtin_amdgcn_mfma_f32_16x16x32_bf16(qrf[ks], kif, kx[c], 0, 0, 0);
        kx[c] = __builtin_amdgcn_mfma_f32_16x16x32_bf16(qif[ks], krf, kx[c], 0, 0, 0);
      }
    }

    // magnitude logits + online softmax
    const bool diag = (jt == ntiles - 1);
#pragma unroll
    for (int r = 0; r < 4; r++) {
      float Lv[4];
#pragma unroll
      for (int c = 0; c < 4; c++) {
        const float ar_ = (k1[c][r] - k2[c][r]) * scale;
        const float ai_ = kx[c][r] * scale;
        const float arr = ar_ + eps * ai_;
        const float aii = ai_ - eps * ar_;
        const float mag = sqrtf(arr * arr + aii * aii + 1e-6f);
        float L = mag * cfac;
        if (diag) {
          const int gi = i0 + w * 16 + quad * 4 + r;
          const int gj = j0 + c * 16 + lcol;
          if (gj > gi) L = -1e30f;
        }
        Lv[c] = L;
      }
      float mt = fmaxf(fmaxf(Lv[0], Lv[1]), fmaxf(Lv[2], Lv[3]));
#pragma unroll
      for (int off = 1; off < 16; off <<= 1)
        mt = fmaxf(mt, __shfl_xor(mt, off, 64));
      const float mn = fmaxf(m_i[r], mt);
      const float al = __expf(m_i[r] - mn);
      m_i[r] = mn;
      float rs = 0.f;
      const int prow = (w * 16 + quad * 4 + r) * LDK;
#pragma unroll
      for (int c = 0; c < 4; c++) {
        const float p = __expf(Lv[c] - mn);
        Ps[prow + c * 16 + lcol] = f2bf(p);
        rs += p;
      }
#pragma unroll
      for (int off = 1; off < 16; off <<= 1)
        rs += __shfl_xor(rs, off, 64);
      l_i[r] = l_i[r] * al + rs;
#pragma unroll
      for (int c = 0; c < 4; c++) { aOr[c][r] *= al; aOi[c][r] *= al; }
    }

    // PV (wave-private P rows; lgkmcnt covers write->read, no barrier)
#pragma unroll
    for (int ks = 0; ks < 2; ks++) {
      bf16x8 pf = *(const bf16x8*)&Ps[(w * 16 + lcol) * LDK + ks * 32 + quad * 8];
#pragma unroll
      for (int c = 0; c < 4; c++) {
        const int off = (c * 16 + lcol) * LDK + ks * 32 + quad * 8;
        bf16x8 vrf = *(const bf16x8*)&VTr[off];
        bf16x8 vif = *(const bf16x8*)&VTi[off];
        aOr[c] = __builtin_amdgcn_mfma_f32_16x16x32_bf16(pf, vrf, aOr[c], 0, 0, 0);
        aOi[c] = __builtin_amdgcn_mfma_f32_16x16x32_bf16(pf, vif, aOi[c], 0, 0, 0);
      }
    }
  }

  // epilogue: normalize, write bf16 row-major (s, DIM)
  float inv[4];
#pragma unroll
  for (int r = 0; r < 4; r++) inv[r] = 1.f / l_i[r];
#pragma unroll
  for (int c = 0; c < 4; c++) {
#pragma unroll
    for (int r = 0; r < 4; r++) {
      const int row = i0 + w * 16 + quad * 4 + r;
      const int col = h * HD + c * 16 + lcol;
      Or[(size_t)row * DIM + col] = f2bf(aOr[c][r] * inv[r]);
      Oi[(size_t)row * DIM + col] = f2bf(aOi[c][r] * inv[r]);
    }
  }
}

// ---------------------------------------------------------------------------
extern "C" void kernel_launch(void* const* d_in, const int* in_sizes, int n_in,
                              void* d_out, int out_size, void* d_ws, size_t ws_size,
                              hipStream_t stream)
{
  const float* real = (const float*)d_in[0];
  const float* imag = (const float*)d_in[1];
  const float* Wq_r = (const float*)d_in[2];
  const float* bq_r = (const float*)d_in[3];
  const float* Wk_r = (const float*)d_in[4];
  const float* bk_r = (const float*)d_in[5];
  const float* Wv_r = (const float*)d_in[6];
  const float* bv_r = (const float*)d_in[7];
  const float* Wq_i = (const float*)d_in[8];
  const float* bq_i = (const float*)d_in[9];
  const float* Wk_i = (const float*)d_in[10];
  const float* bk_i = (const float*)d_in[11];
  const float* Wv_i = (const float*)d_in[12];
  const float* bv_i = (const float*)d_in[13];
  const float* Wo_r = (const float*)d_in[14];
  const float* bo_r = (const float*)d_in[15];
  const float* Wo_i = (const float*)d_in[16];
  const float* bo_i = (const float*)d_in[17];
  const float* phase = (const float*)d_in[18];
  const float* ent   = (const float*)d_in[19];
  const float* freqs = (const float*)d_in[20];
  const float* p_is  = (const float*)d_in[21];
  const float* p_at  = (const float*)d_in[22];
  const float* p_ce  = (const float*)d_in[23];

  unsigned short* ws = (unsigned short*)d_ws;
  const size_t SL = (size_t)S_LEN * DIM;   // 2,097,152
  const size_t WL = (size_t)DIM * DIM;     // 1,048,576

  unsigned short* realb = ws;               // 2M
  unsigned short* imagb = realb + SL;       // 2M
  unsigned short* Wb    = imagb + SL;       // 8 x 1M (Wq_r,Wk_r,Wv_r,Wq_i,Wk_i,Wv_i,Wo_r,Wo_i)
  unsigned short* q_r   = Wb + 8 * WL;
  unsigned short* k_r   = q_r + SL;
  unsigned short* v_r   = k_r + SL;
  unsigned short* q_i   = v_r + SL;
  unsigned short* k_i   = q_i + SL;
  unsigned short* v_i   = k_i + SL;
  unsigned short* Qr    = v_i + SL;
  unsigned short* Qi    = Qr + SL;
  unsigned short* Kr    = Qi + SL;
  unsigned short* Ki    = Kr + SL;
  unsigned short* O_r   = q_r;   // dead after entangle
  unsigned short* O_i   = q_i;

  float* out_r = (float*)d_out;
  float* out_i = out_r + SL;

  // 0. fp32 -> bf16 conversions
  ConvBatch cb;
  cb.src[0] = real; cb.dst[0] = realb; cb.n[0] = (int)SL;
  cb.src[1] = imag; cb.dst[1] = imagb; cb.n[1] = (int)SL;
  const float* wsrc[8] = {Wq_r, Wk_r, Wv_r, Wq_i, Wk_i, Wv_i, Wo_r, Wo_i};
  for (int i = 0; i < 8; i++) {
    cb.src[2 + i] = wsrc[i];
    cb.dst[2 + i] = Wb + (size_t)i * WL;
    cb.n[2 + i] = (int)WL;
  }
  conv_kernel<<<dim3(1024, 10), dim3(256), 0, stream>>>(cb);

  // 1. six input projections -> bf16 head-major [h][s][d]
  BGemm g1;
  g1.A[0] = realb; g1.A[1] = realb; g1.A[2] = realb;
  g1.A[3] = imagb; g1.A[4] = imagb; g1.A[5] = imagb;
  for (int i = 0; i < 6; i++) g1.W[i] = Wb + (size_t)i * WL;
  g1.bias[0] = bq_r; g1.bias[1] = bk_r; g1.bias[2] = bv_r;
  g1.bias[3] = bq_i; g1.bias[4] = bk_i; g1.bias[5] = bv_i;
  g1.C[0] = q_r; g1.C[1] = k_r; g1.C[2] = v_r;
  g1.C[3] = q_i; g1.C[4] = k_i; g1.C[5] = v_i;
  gemm_mfma_kernel<<<dim3(8, 16, 6), dim3(256), 0, stream>>>(g1, 1);

  // 2. RoPE in-place (bf16)
  rope_kernel<<<dim3(8192), dim3(256), 0, stream>>>(q_r, k_r, q_i, k_i, freqs);

  // 3. entangle + phase (bf16)
  entangle_kernel<<<dim3(512, 1, 2), dim3(256), 0, stream>>>(
      q_r, q_i, Qr, Qi, k_r, k_i, Kr, Ki, ent, phase);

  // 4. flash attention (MFMA, bf16 in/out) -> O row-major (s, DIM)
  flash_mfma_kernel<<<dim3(S_LEN / 64, NH), dim3(256), 0, stream>>>(
      Qr, Qi, Kr, Ki, v_r, v_i, O_r, O_i, p_is, p_at, p_ce);

  // 5. output projections -> fp32 d_out
  BGemm g2 = {};
  g2.A[0] = O_r; g2.A[1] = O_i;
  g2.W[0] = Wb + 6 * WL; g2.W[1] = Wb + 7 * WL;
  g2.bias[0] = bo_r; g2.bias[1] = bo_i;
  g2.C[0] = out_r; g2.C[1] = out_i;
  gemm_mfma_kernel<<<dim3(8, 16, 2), dim3(256), 0, stream>>>(g2, 0);
}

// Round 4
// 333.734 us; speedup vs baseline: 6.2698x; 1.3504x over previous
//
#include <hip/hip_runtime.h>
#include <cstddef>
#include <cstdint>
#include <math.h>

#define S_LEN 2048
#define DIM 1024
#define NH 16
#define HD 64

typedef __attribute__((ext_vector_type(8))) short bf16x8;
typedef __attribute__((ext_vector_type(8))) unsigned short u16x8;
typedef __attribute__((ext_vector_type(4))) float f32x4;

__device__ inline unsigned short f2bf(float x) {
  union { float f; unsigned u; } v; v.f = x;
  unsigned r = v.u + 0x7FFFu + ((v.u >> 16) & 1u);   // round-to-nearest-even
  return (unsigned short)(r >> 16);
}
__device__ inline float bf2f(unsigned short x) {
  union { unsigned u; float f; } v; v.u = ((unsigned)x) << 16; return v.f;
}

#define GLOAD_LDS16(g, l)                                              \
  __builtin_amdgcn_global_load_lds(                                    \
      (const __attribute__((address_space(1))) void*)(g),              \
      (__attribute__((address_space(3))) void*)(l), 16, 0, 0)

// ---------------------------------------------------------------------------
// fp32 -> bf16 conversion for 10 tensors.
// ---------------------------------------------------------------------------
struct ConvBatch {
  const float* src[10];
  unsigned short* dst[10];
  int n[10];
};

__global__ __launch_bounds__(256) void conv_kernel(ConvBatch cb)
{
  const int y = blockIdx.y;
  const int i = (blockIdx.x * 256 + threadIdx.x) * 8;
  if (i >= cb.n[y]) return;
  const float* s = cb.src[y];
  float4 a = *(const float4*)(s + i);
  float4 b = *(const float4*)(s + i + 4);
  u16x8 o;
  o[0] = f2bf(a.x); o[1] = f2bf(a.y); o[2] = f2bf(a.z); o[3] = f2bf(a.w);
  o[4] = f2bf(b.x); o[5] = f2bf(b.y); o[6] = f2bf(b.z); o[7] = f2bf(b.w);
  *(u16x8*)(cb.dst[y] + i) = o;
}

// ---------------------------------------------------------------------------
// bf16 MFMA GEMM: C = A @ W^T + bias, m97 structure (128x128, BK=32,
// global_load_lds w=16). Per-z output mode:
//   0: fp32 row-major (s, DIM)
//   1: bf16 head-major [h][s][d]
//   2: bf16 transposed head-major [h][d][s]   (for V)
// ---------------------------------------------------------------------------
struct BGemm {
  const unsigned short* A[6];
  const unsigned short* W[6];
  const float* bias[6];
  void* C[6];
  int mode[6];
};

__global__ __launch_bounds__(256) void gemm_mfma_kernel(BGemm gb)
{
  constexpr int K = DIM;
  const int z = blockIdx.z;
  const unsigned short* __restrict__ A = gb.A[z];
  const unsigned short* __restrict__ W = gb.W[z];
  const float* __restrict__ bias = gb.bias[z];
  const int mode = gb.mode[z];

  __shared__ __align__(16) unsigned short As[128 * 32];
  __shared__ __align__(16) unsigned short Ws[128 * 32];

  const int t    = threadIdx.x;
  const int lane = t & 63;
  const int w    = t >> 6;
  const int wm   = w >> 1, wn = w & 1;
  const int quad = lane >> 4, lcol = lane & 15;
  const int m0   = blockIdx.y * 128;
  const int n0   = blockIdx.x * 128;

  const int srow = t >> 2;
  const int sk8  = (t & 3) * 8;

  f32x4 acc[4][4];
#pragma unroll
  for (int i = 0; i < 4; i++)
#pragma unroll
    for (int j = 0; j < 4; j++)
#pragma unroll
      for (int r = 0; r < 4; r++) acc[i][j][r] = 0.f;

  for (int k0 = 0; k0 < K; k0 += 32) {
    __syncthreads();
#pragma unroll
    for (int p = 0; p < 2; p++) {
      const unsigned short* ga = A + (size_t)(m0 + p * 64 + srow) * K + k0 + sk8;
      GLOAD_LDS16(ga, As + (size_t)(p * 256 + w * 64) * 8);
      const unsigned short* gw = W + (size_t)(n0 + p * 64 + srow) * K + k0 + sk8;
      GLOAD_LDS16(gw, Ws + (size_t)(p * 256 + w * 64) * 8);
    }
    __syncthreads();

    bf16x8 af[4], bfr[4];
#pragma unroll
    for (int mi = 0; mi < 4; mi++)
      af[mi] = *(const bf16x8*)&As[(wm * 64 + mi * 16 + lcol) * 32 + quad * 8];
#pragma unroll
    for (int ni = 0; ni < 4; ni++)
      bfr[ni] = *(const bf16x8*)&Ws[(wn * 64 + ni * 16 + lcol) * 32 + quad * 8];
#pragma unroll
    for (int mi = 0; mi < 4; mi++)
#pragma unroll
      for (int ni = 0; ni < 4; ni++)
        acc[mi][ni] = __builtin_amdgcn_mfma_f32_16x16x32_bf16(af[mi], bfr[ni], acc[mi][ni], 0, 0, 0);
  }

#pragma unroll
  for (int mi = 0; mi < 4; mi++) {
#pragma unroll
    for (int ni = 0; ni < 4; ni++) {
#pragma unroll
      for (int r = 0; r < 4; r++) {
        const int grow = m0 + wm * 64 + mi * 16 + quad * 4 + r;
        const int gcol = n0 + wn * 64 + ni * 16 + lcol;
        const float v = acc[mi][ni][r] + bias[gcol];
        if (mode == 0) {
          ((float*)gb.C[z])[(size_t)grow * DIM + gcol] = v;
        } else if (mode == 1) {
          const int hh = gcol >> 6, d = gcol & 63;
          ((unsigned short*)gb.C[z])[((size_t)hh * S_LEN + grow) * HD + d] = f2bf(v);
        } else {
          const int hh = gcol >> 6, d = gcol & 63;
          ((unsigned short*)gb.C[z])[((size_t)hh * HD + d) * S_LEN + grow] = f2bf(v);
        }
      }
    }
  }
}

// ---------------------------------------------------------------------------
// RoPE (interleaved) on first 32 dims of each head, in-place, bf16.
// ---------------------------------------------------------------------------
__global__ __launch_bounds__(256) void rope_kernel(
    unsigned short* q_r, unsigned short* k_r,
    unsigned short* q_i, unsigned short* k_i,
    const float* __restrict__ freqs)
{
  const int gid = blockIdx.x * 256 + threadIdx.x;
  const int j  = gid & 15;
  const int s  = (gid >> 4) & (S_LEN - 1);
  const int h  = (gid >> 15) & (NH - 1);
  const int tz = gid >> 19;
  unsigned short* buf = (tz == 0) ? q_r : (tz == 1) ? k_r : (tz == 2) ? q_i : k_i;

  const float ang = (float)s * freqs[j];
  float sn, cs;
  sincosf(ang, &sn, &cs);

  const size_t base = ((size_t)h * S_LEN + s) * HD + 2 * j;
  ushort2 xv = *(const ushort2*)(buf + base);
  const float x1 = bf2f(xv.x), x2 = bf2f(xv.y);
  ushort2 ov;
  ov.x = f2bf(x1 * cs - x2 * sn);
  ov.y = f2bf(x1 * sn + x2 * cs);
  *(ushort2*)(buf + base) = ov;
}

// ---------------------------------------------------------------------------
// Entanglement (head mix) + phase rotation, bf16 in/out, fp32 math.
// ---------------------------------------------------------------------------
__global__ __launch_bounds__(256) void entangle_kernel(
    const unsigned short* __restrict__ qr_in, const unsigned short* __restrict__ qi_in,
    unsigned short* __restrict__ qr_out, unsigned short* __restrict__ qi_out,
    const unsigned short* __restrict__ kr_in, const unsigned short* __restrict__ ki_in,
    unsigned short* __restrict__ kr_out, unsigned short* __restrict__ ki_out,
    const float* __restrict__ E, const float* __restrict__ phase)
{
  const int z = blockIdx.z;
  const unsigned short* inR = z ? kr_in : qr_in;
  const unsigned short* inI = z ? ki_in : qi_in;
  unsigned short* outR = z ? kr_out : qr_out;
  unsigned short* outI = z ? ki_out : qi_out;

  __shared__ float Es[NH * NH];
  const int t = threadIdx.x;
  Es[t] = E[t];
  __syncthreads();

  const int idx = blockIdx.x * 256 + t;
  const int s = idx >> 6;
  const int d = idx & 63;

  float vr[NH], vi[NH];
#pragma unroll
  for (int h = 0; h < NH; h++) {
    const size_t off = ((size_t)h * S_LEN + s) * HD + d;
    vr[h] = bf2f(inR[off]);
    vi[h] = bf2f(inI[off]);
  }

#pragma unroll
  for (int x = 0; x < NH; x++) {
    float er = 0.f, ei = 0.f;
#pragma unroll
    for (int h = 0; h < NH; h++) {
      const float e = Es[h * NH + x];
      er += vr[h] * e;
      ei += vi[h] * e;
    }
    const float ph = phase[x * HD + d];
    float ps, pc;
    sincosf(ph, &ps, &pc);
    const size_t off = ((size_t)x * S_LEN + s) * HD + d;
    outR[off] = f2bf(er * pc - ei * ps);
    outI[off] = f2bf(er * ps + ei * pc);
  }
}

// ---------------------------------------------------------------------------
// Flash attention on MFMA (bf16 16x16x32), causal-balanced:
// grid (16, NH); block x handles i-tiles {x, 31-x} sequentially -> every
// block does exactly 33 kv-tiles (no tail). V arrives pre-transposed
// [h][d][s] so ALL staging is bf16x8 vector ds_write_b128 (no scalar
// transpose writes). Next kv-tile is register-prefetched during compute.
// ---------------------------------------------------------------------------
#define LDK 72   // 144 B row stride: multiple of 16 B, breaks 2^k strides

__global__ __launch_bounds__(256) void flash_mfma_kernel(
    const unsigned short* __restrict__ Qr, const unsigned short* __restrict__ Qi,
    const unsigned short* __restrict__ Kr, const unsigned short* __restrict__ Ki,
    const unsigned short* __restrict__ VtR, const unsigned short* __restrict__ VtI,
    unsigned short* __restrict__ Or, unsigned short* __restrict__ Oi,
    const float* __restrict__ p_is, const float* __restrict__ p_at,
    const float* __restrict__ p_ce)
{
  __shared__ __align__(16) unsigned short Krs[64 * LDK];
  __shared__ __align__(16) unsigned short Kis[64 * LDK];
  __shared__ __align__(16) unsigned short VTr[64 * LDK];
  __shared__ __align__(16) unsigned short VTi[64 * LDK];
  __shared__ __align__(16) unsigned short Ps [64 * LDK];

  const int t    = threadIdx.x;
  const int lane = t & 63;
  const int w    = t >> 6;
  const int quad = lane >> 4;
  const int lcol = lane & 15;
  const int h    = blockIdx.y;

  const float strength = 1.f / (1.f + expf(-p_is[0]));
  const float temp     = fmaxf(expf(p_at[0]), 0.1f);
  const float cfac     = strength / temp;
  const float eps      = 0.03f / (1.f + expf(-p_ce[0]));
  const float scale    = 0.125f;

  // staging address components (per thread, reused every tile)
  const int srow = t >> 3;          // 0..31 (+32 on second chunk)
  const int sd0  = (t & 7) * 8;     // 0..56 step 8

  bf16x8 pk[2], pki[2], pv[2], pvi[2];   // prefetch registers

  for (int run = 0; run < 2; run++) {
    const int itile = (run == 0) ? blockIdx.x : 31 - blockIdx.x;
    const int i0 = itile * 64;

    // Q fragments straight from global bf16
    bf16x8 qrf[2], qif[2];
    {
      const int qrow = i0 + w * 16 + lcol;
      const size_t base = ((size_t)h * S_LEN + qrow) * HD;
#pragma unroll
      for (int ks = 0; ks < 2; ks++) {
        qrf[ks] = *(const bf16x8*)(Qr + base + ks * 32 + quad * 8);
        qif[ks] = *(const bf16x8*)(Qi + base + ks * 32 + quad * 8);
      }
    }

    float m_i[4], l_i[4];
    f32x4 aOr[4], aOi[4];
#pragma unroll
    for (int r = 0; r < 4; r++) { m_i[r] = -1e30f; l_i[r] = 0.f; }
#pragma unroll
    for (int c = 0; c < 4; c++)
#pragma unroll
      for (int r = 0; r < 4; r++) { aOr[c][r] = 0.f; aOi[c][r] = 0.f; }

    const int ntiles = itile + 1;

    // prefetch tile 0
    {
      const size_t kb = ((size_t)h * S_LEN) * HD;
#pragma unroll
      for (int it = 0; it < 2; it++) {
        const int row = srow + it * 32;
        pk [it] = *(const bf16x8*)(Kr  + kb + (size_t)row * HD + sd0);
        pki[it] = *(const bf16x8*)(Ki  + kb + (size_t)row * HD + sd0);
        pv [it] = *(const bf16x8*)(VtR + ((size_t)h * HD + row) * S_LEN + sd0);
        pvi[it] = *(const bf16x8*)(VtI + ((size_t)h * HD + row) * S_LEN + sd0);
      }
    }

    for (int jt = 0; jt < ntiles; jt++) {
      __syncthreads();   // all waves done reading previous tile's LDS
#pragma unroll
      for (int it = 0; it < 2; it++) {
        const int row = srow + it * 32;
        *(bf16x8*)&Krs[row * LDK + sd0] = pk [it];
        *(bf16x8*)&Kis[row * LDK + sd0] = pki[it];
        *(bf16x8*)&VTr[row * LDK + sd0] = pv [it];
        *(bf16x8*)&VTi[row * LDK + sd0] = pvi[it];
      }
      __syncthreads();   // LDS tiles ready

      // prefetch next tile (overlaps compute below)
      if (jt + 1 < ntiles) {
        const int j0n = (jt + 1) * 64;
        const size_t kb = ((size_t)h * S_LEN + j0n) * HD;
#pragma unroll
        for (int it = 0; it < 2; it++) {
          const int row = srow + it * 32;
          pk [it] = *(const bf16x8*)(Kr  + kb + (size_t)row * HD + sd0);
          pki[it] = *(const bf16x8*)(Ki  + kb + (size_t)row * HD + sd0);
          pv [it] = *(const bf16x8*)(VtR + ((size_t)h * HD + row) * S_LEN + j0n + sd0);
          pvi[it] = *(const bf16x8*)(VtI + ((size_t)h * HD + row) * S_LEN + j0n + sd0);
        }
      }

      // ---- scores ----
      f32x4 k1[4], k2[4], kx[4];
#pragma unroll
      for (int c = 0; c < 4; c++)
#pragma unroll
        for (int r = 0; r < 4; r++) { k1[c][r] = 0.f; k2[c][r] = 0.f; kx[c][r] = 0.f; }
#pragma unroll
      for (int ks = 0; ks < 2; ks++) {
#pragma unroll
        for (int c = 0; c < 4; c++) {
          const int off = (c * 16 + lcol) * LDK + ks * 32 + quad * 8;
          bf16x8 krf = *(const bf16x8*)&Krs[off];
          bf16x8 kif = *(const bf16x8*)&Kis[off];
          k1[c] = __builtin_amdgcn_mfma_f32_16x16x32_bf16(qrf[ks], krf, k1[c], 0, 0, 0);
          k2[c] = __builtin_amdgcn_mfma_f32_16x16x32_bf16(qif[ks], kif, k2[c], 0, 0, 0);
          kx[c] = __builtin_amdgcn_mfma_f32_16x16x32_bf16(qrf[ks], kif, kx[c], 0, 0, 0);
          kx[c] = __builtin_amdgcn_mfma_f32_16x16x32_bf16(qif[ks], krf, kx[c], 0, 0, 0);
        }
      }

      // ---- magnitude logits + online softmax ----
      const bool diag = (jt == ntiles - 1);
      const int j0 = jt * 64;
#pragma unroll
      for (int r = 0; r < 4; r++) {
        float Lv[4];
#pragma unroll
        for (int c = 0; c < 4; c++) {
          const float ar_ = (k1[c][r] - k2[c][r]) * scale;
          const float ai_ = kx[c][r] * scale;
          const float arr = ar_ + eps * ai_;
          const float aii = ai_ - eps * ar_;
          const float mag = sqrtf(arr * arr + aii * aii + 1e-6f);
          float L = mag * cfac;
          if (diag) {
            const int gi = i0 + w * 16 + quad * 4 + r;
            const int gj = j0 + c * 16 + lcol;
            if (gj > gi) L = -1e30f;
          }
          Lv[c] = L;
        }
        float mt = fmaxf(fmaxf(Lv[0], Lv[1]), fmaxf(Lv[2], Lv[3]));
#pragma unroll
        for (int off = 1; off < 16; off <<= 1)
          mt = fmaxf(mt, __shfl_xor(mt, off, 64));
        const float mn = fmaxf(m_i[r], mt);
        const float al = __expf(m_i[r] - mn);
        m_i[r] = mn;
        float rs = 0.f;
        const int prow = (w * 16 + quad * 4 + r) * LDK;
#pragma unroll
        for (int c = 0; c < 4; c++) {
          const float p = __expf(Lv[c] - mn);
          Ps[prow + c * 16 + lcol] = f2bf(p);
          rs += p;
        }
#pragma unroll
        for (int off = 1; off < 16; off <<= 1)
          rs += __shfl_xor(rs, off, 64);
        l_i[r] = l_i[r] * al + rs;
#pragma unroll
        for (int c = 0; c < 4; c++) { aOr[c][r] *= al; aOi[c][r] *= al; }
      }

      // ---- PV (wave-private P rows; lgkmcnt covers write->read) ----
#pragma unroll
      for (int ks = 0; ks < 2; ks++) {
        bf16x8 pf = *(const bf16x8*)&Ps[(w * 16 + lcol) * LDK + ks * 32 + quad * 8];
#pragma unroll
        for (int c = 0; c < 4; c++) {
          const int off = (c * 16 + lcol) * LDK + ks * 32 + quad * 8;
          bf16x8 vrf = *(const bf16x8*)&VTr[off];
          bf16x8 vif = *(const bf16x8*)&VTi[off];
          aOr[c] = __builtin_amdgcn_mfma_f32_16x16x32_bf16(pf, vrf, aOr[c], 0, 0, 0);
          aOi[c] = __builtin_amdgcn_mfma_f32_16x16x32_bf16(pf, vif, aOi[c], 0, 0, 0);
        }
      }
    }

    // epilogue: normalize, write bf16 row-major (s, DIM)
    float inv[4];
#pragma unroll
    for (int r = 0; r < 4; r++) inv[r] = 1.f / l_i[r];
#pragma unroll
    for (int c = 0; c < 4; c++) {
#pragma unroll
      for (int r = 0; r < 4; r++) {
        const int row = i0 + w * 16 + quad * 4 + r;
        const int col = h * HD + c * 16 + lcol;
        Or[(size_t)row * DIM + col] = f2bf(aOr[c][r] * inv[r]);
        Oi[(size_t)row * DIM + col] = f2bf(aOi[c][r] * inv[r]);
      }
    }
  }
}

// ---------------------------------------------------------------------------
extern "C" void kernel_launch(void* const* d_in, const int* in_sizes, int n_in,
                              void* d_out, int out_size, void* d_ws, size_t ws_size,
                              hipStream_t stream)
{
  const float* real = (const float*)d_in[0];
  const float* imag = (const float*)d_in[1];
  const float* Wq_r = (const float*)d_in[2];
  const float* bq_r = (const float*)d_in[3];
  const float* Wk_r = (const float*)d_in[4];
  const float* bk_r = (const float*)d_in[5];
  const float* Wv_r = (const float*)d_in[6];
  const float* bv_r = (const float*)d_in[7];
  const float* Wq_i = (const float*)d_in[8];
  const float* bq_i = (const float*)d_in[9];
  const float* Wk_i = (const float*)d_in[10];
  const float* bk_i = (const float*)d_in[11];
  const float* Wv_i = (const float*)d_in[12];
  const float* bv_i = (const float*)d_in[13];
  const float* Wo_r = (const float*)d_in[14];
  const float* bo_r = (const float*)d_in[15];
  const float* Wo_i = (const float*)d_in[16];
  const float* bo_i = (const float*)d_in[17];
  const float* phase = (const float*)d_in[18];
  const float* ent   = (const float*)d_in[19];
  const float* freqs = (const float*)d_in[20];
  const float* p_is  = (const float*)d_in[21];
  const float* p_at  = (const float*)d_in[22];
  const float* p_ce  = (const float*)d_in[23];

  unsigned short* ws = (unsigned short*)d_ws;
  const size_t SL = (size_t)S_LEN * DIM;
  const size_t WL = (size_t)DIM * DIM;

  unsigned short* realb = ws;
  unsigned short* imagb = realb + SL;
  unsigned short* Wb    = imagb + SL;
  unsigned short* q_r   = Wb + 8 * WL;
  unsigned short* k_r   = q_r + SL;
  unsigned short* v_r   = k_r + SL;     // [h][d][s] transposed
  unsigned short* q_i   = v_r + SL;
  unsigned short* k_i   = q_i + SL;
  unsigned short* v_i   = k_i + SL;     // [h][d][s] transposed
  unsigned short* Qr    = v_i + SL;
  unsigned short* Qi    = Qr + SL;
  unsigned short* Kr    = Qi + SL;
  unsigned short* Ki    = Kr + SL;
  unsigned short* O_r   = q_r;   // dead after entangle
  unsigned short* O_i   = q_i;

  float* out_r = (float*)d_out;
  float* out_i = out_r + SL;

  // 0. fp32 -> bf16 conversions
  ConvBatch cb;
  cb.src[0] = real; cb.dst[0] = realb; cb.n[0] = (int)SL;
  cb.src[1] = imag; cb.dst[1] = imagb; cb.n[1] = (int)SL;
  const float* wsrc[8] = {Wq_r, Wk_r, Wv_r, Wq_i, Wk_i, Wv_i, Wo_r, Wo_i};
  for (int i = 0; i < 8; i++) {
    cb.src[2 + i] = wsrc[i];
    cb.dst[2 + i] = Wb + (size_t)i * WL;
    cb.n[2 + i] = (int)WL;
  }
  conv_kernel<<<dim3(1024, 10), dim3(256), 0, stream>>>(cb);

  // 1. six input projections; Q/K head-major, V transposed head-major
  BGemm g1;
  g1.A[0] = realb; g1.A[1] = realb; g1.A[2] = realb;
  g1.A[3] = imagb; g1.A[4] = imagb; g1.A[5] = imagb;
  for (int i = 0; i < 6; i++) g1.W[i] = Wb + (size_t)i * WL;
  g1.bias[0] = bq_r; g1.bias[1] = bk_r; g1.bias[2] = bv_r;
  g1.bias[3] = bq_i; g1.bias[4] = bk_i; g1.bias[5] = bv_i;
  g1.C[0] = q_r; g1.C[1] = k_r; g1.C[2] = v_r;
  g1.C[3] = q_i; g1.C[4] = k_i; g1.C[5] = v_i;
  g1.mode[0] = 1; g1.mode[1] = 1; g1.mode[2] = 2;
  g1.mode[3] = 1; g1.mode[4] = 1; g1.mode[5] = 2;
  gemm_mfma_kernel<<<dim3(8, 16, 6), dim3(256), 0, stream>>>(g1);

  // 2. RoPE in-place (bf16) on q/k only
  rope_kernel<<<dim3(8192), dim3(256), 0, stream>>>(q_r, k_r, q_i, k_i, freqs);

  // 3. entangle + phase (bf16)
  entangle_kernel<<<dim3(512, 1, 2), dim3(256), 0, stream>>>(
      q_r, q_i, Qr, Qi, k_r, k_i, Kr, Ki, ent, phase);

  // 4. flash attention (MFMA, balanced paired i-tiles) -> O row-major (s, DIM)
  flash_mfma_kernel<<<dim3(16, NH), dim3(256), 0, stream>>>(
      Qr, Qi, Kr, Ki, v_r, v_i, O_r, O_i, p_is, p_at, p_ce);

  // 5. output projections -> fp32 d_out
  BGemm g2 = {};
  g2.A[0] = O_r; g2.A[1] = O_i;
  g2.W[0] = Wb + 6 * WL; g2.W[1] = Wb + 7 * WL;
  g2.bias[0] = bo_r; g2.bias[1] = bo_i;
  g2.C[0] = out_r; g2.C[1] = out_i;
  g2.mode[0] = 0; g2.mode[1] = 0;
  gemm_mfma_kernel<<<dim3(8, 16, 2), dim3(256), 0, stream>>>(g2);
}